// Round 12
// baseline (229.116 us; speedup 1.0000x reference)
//
#include <hip/hip_runtime.h>

#define NN 40000
#define NE 640000
#define NSB ((NN + 255) / 256)  // 157 alloc blocks
#define NNP (NN + 64)           // padded rows for OOB-tolerant mfma A loads

typedef unsigned int uint32;
typedef unsigned short ushort;
typedef __attribute__((ext_vector_type(8))) short bf16x8;
typedef __attribute__((ext_vector_type(4))) float f32x4;

static __device__ __forceinline__ float lrelu(float x) { return x > 0.0f ? x : 0.2f * x; }

static __device__ __forceinline__ float wave_max(float v) {
    for (int off = 32; off; off >>= 1) v = fmaxf(v, __shfl_xor(v, off));
    return v;
}
static __device__ __forceinline__ float wave_sum(float v) {
    for (int off = 32; off; off >>= 1) v += __shfl_xor(v, off);
    return v;
}

// bf16 RNE helpers
static __device__ __forceinline__ uint32 bfr(float x) {
    uint32 u = __float_as_uint(x);
    return u + 0x7FFFu + ((u >> 16) & 1u);
}
static __device__ __forceinline__ ushort bf16of(float x) { return (ushort)(bfr(x) >> 16); }
static __device__ __forceinline__ uint32 pack2(float a, float b) {
    return (bfr(a) >> 16) | (bfr(b) & 0xFFFF0000u);
}
static __device__ __forceinline__ float lo16(uint32 v) { return __uint_as_float(v << 16); }
static __device__ __forceinline__ float hi16(uint32 v) { return __uint_as_float(v & 0xFFFF0000u); }

// ------- fused casts + zero init: y=0 x->bf16, y=1..4 weight transpose-casts, y=5 zero -------
__global__ void k_cast(const float* __restrict__ x, ushort* __restrict__ xb,
                       const float* __restrict__ W1, const float* __restrict__ Wg1,
                       const float* __restrict__ W2, const float* __restrict__ Wg2,
                       ushort* __restrict__ t1, ushort* __restrict__ tg1,
                       ushort* __restrict__ t2, ushort* __restrict__ tg2,
                       int* __restrict__ cnt, int* __restrict__ gctr) {
    if (blockIdx.y == 0) {
        int base = (blockIdx.x * 256 + threadIdx.x) * 4;
        if (base < NN * 128) {
            float4 v = *(const float4*)&x[base];
            ushort4 o;
            o.x = bf16of(v.x);
            o.y = bf16of(v.y);
            o.z = bf16of(v.z);
            o.w = bf16of(v.w);
            *(ushort4*)&xb[base] = o;
        }
        return;
    }
    if (blockIdx.y == 5) {
        int i = blockIdx.x * 256 + threadIdx.x;
        if (i < NN) cnt[i] = 0;
        if (i == 0) *gctr = 0;
        return;
    }
    const float* W;
    ushort* T;
    int K, N;
    switch (blockIdx.y) {
        case 1: W = W1; T = t1; K = 128; N = 128; break;
        case 2: W = Wg1; T = tg1; K = 128; N = 128; break;
        case 3: W = W2; T = t2; K = 128; N = 64; break;
        default: W = Wg2; T = tg2; K = 64; N = 64; break;
    }
    int idx = blockIdx.x * 256 + threadIdx.x;
    if (idx < K * N) {
        int n = idx / K, k = idx % K;
        T[idx] = bf16of(W[k * N + n]);
    }
}

// ---------------- CSR build: count(+rank) -> alloc (bump) -> fill (no atomics) ----------------
__global__ void k_count(const int* __restrict__ dst, int* __restrict__ cnt,
                        int* __restrict__ rank) {
    int e = blockIdx.x * blockDim.x + threadIdx.x;
    if (e < NE) rank[e] = atomicAdd(&cnt[dst[e]], 1);
}
__global__ void k_alloc(const int* __restrict__ cnt, int* __restrict__ gctr,
                        int2* __restrict__ rseg, float* __restrict__ dinv) {
    __shared__ int wsums[4];
    __shared__ int sbase;
    int t = threadIdx.x, lane = t & 63, w = t >> 6;
    int i = blockIdx.x * 256 + t;
    int v = (i < NN) ? cnt[i] : 0;
    int x = v;
    for (int off = 1; off < 64; off <<= 1) {
        int u = __shfl_up(x, off);
        if (lane >= off) x += u;
    }
    if (lane == 63) wsums[w] = x;
    __syncthreads();
    if (t == 0) sbase = atomicAdd(gctr, wsums[0] + wsums[1] + wsums[2] + wsums[3]);
    __syncthreads();
    int wofs = 0;
    for (int k = 0; k < w; ++k) wofs += wsums[k];
    int excl = sbase + wofs + x - v;
    if (i < NN) {
        rseg[i] = make_int2(excl, excl + v);
        dinv[i] = rsqrtf(1.0f + (float)v);
    }
}
__global__ void k_fill(const int* __restrict__ src, const int* __restrict__ dst,
                       const int* __restrict__ rank, const int2* __restrict__ rseg,
                       int* __restrict__ csr_src) {
    int e = blockIdx.x * blockDim.x + threadIdx.x;
    if (e < NE) {
        int d = dst[e];
        csr_src[rseg[d].x + rank[e]] = src[e];
    }
}

// ---------------- MFMA GEMM: Y16 = bf16(X*W); GAT: fused asrc/adst epilogue ----------------
template <int FIN, int FOUT, bool GAT>
__global__ __launch_bounds__(256) void k_gemm_mfma(const ushort* __restrict__ Xb,
                                                   const ushort* __restrict__ Wt,
                                                   ushort* __restrict__ Y16,
                                                   const float* __restrict__ a_s,
                                                   const float* __restrict__ a_d,
                                                   float* __restrict__ asrc,
                                                   float* __restrict__ adst) {
    constexpr int NT = FOUT / 16;
    const int w = threadIdx.x >> 6, lane = threadIdx.x & 63;
    const int row0 = blockIdx.x * 128 + w * 32;
    const int lr = lane & 15;
    const int lk = (lane >> 4) * 8;

    f32x4 acc[2][NT];
#pragma unroll
    for (int mt = 0; mt < 2; ++mt)
#pragma unroll
        for (int nt = 0; nt < NT; ++nt) acc[mt][nt] = (f32x4){0.f, 0.f, 0.f, 0.f};

#pragma unroll
    for (int ks = 0; ks < FIN / 32; ++ks) {
        bf16x8 a[2], b[NT];
#pragma unroll
        for (int mt = 0; mt < 2; ++mt)
            a[mt] = *(const bf16x8*)&Xb[(size_t)(row0 + mt * 16 + lr) * FIN + ks * 32 + lk];
#pragma unroll
        for (int nt = 0; nt < NT; ++nt)
            b[nt] = *(const bf16x8*)&Wt[(size_t)(nt * 16 + lr) * FIN + ks * 32 + lk];
#pragma unroll
        for (int mt = 0; mt < 2; ++mt)
#pragma unroll
            for (int nt = 0; nt < NT; ++nt)
                acc[mt][nt] =
                    __builtin_amdgcn_mfma_f32_16x16x32_bf16(a[mt], b[nt], acc[mt][nt], 0, 0, 0);
    }

    const int rbase = (lane >> 4) * 4;
#pragma unroll
    for (int mt = 0; mt < 2; ++mt)
#pragma unroll
        for (int nt = 0; nt < NT; ++nt) {
            int col = nt * 16 + lr;
#pragma unroll
            for (int i = 0; i < 4; ++i) {
                int r = row0 + mt * 16 + rbase + i;
                if (r < NN) Y16[(size_t)r * FOUT + col] = bf16of(acc[mt][nt][i]);
            }
        }

    if (GAT) {
#pragma unroll
        for (int mt = 0; mt < 2; ++mt)
#pragma unroll
            for (int i = 0; i < 4; ++i) {
                float ss = 0.0f, dd = 0.0f;
#pragma unroll
                for (int nt = 0; nt < NT; ++nt) {
                    float v = acc[mt][nt][i];
                    ss = fmaf(v, a_s[nt * 16 + lr], ss);
                    dd = fmaf(v, a_d[nt * 16 + lr], dd);
                }
#pragma unroll
                for (int off = 1; off < 16; off <<= 1) {
                    ss += __shfl_xor(ss, off);
                    dd += __shfl_xor(dd, off);
                }
                if (lr == 0) {
                    int r = row0 + mt * 16 + rbase + i;
                    if (r < NN) {
                        asrc[r] = ss;
                        adst[r] = dd;
                    }
                }
            }
    }
}

// ---- bf16 gather steps: 16 independent loads in flight, fp32 accumulate ----
// Shuffle-index safety: cnt <= 64 and j steps by batch size, so max lane index read is 63.
static __device__ __forceinline__ void gath128(const uint32* __restrict__ h16, int lane, int myi,
                                               float myw, int cnt, float* acc) {
    for (int j = 0; j < cnt; j += 16) {
        int s[16];
        float w[16];
#pragma unroll
        for (int u = 0; u < 16; ++u) {
            s[u] = __shfl(myi, j + u);
            w[u] = __shfl(myw, j + u);
        }
        uint32 v[16];
#pragma unroll
        for (int u = 0; u < 16; ++u) v[u] = h16[(size_t)s[u] * 64 + lane];
#pragma unroll
        for (int u = 0; u < 16; ++u) {
            acc[0] = fmaf(w[u], lo16(v[u]), acc[0]);
            acc[1] = fmaf(w[u], hi16(v[u]), acc[1]);
        }
    }
}
static __device__ __forceinline__ void gath64(const uint32* __restrict__ h16, int lane, int myi,
                                              float myw, int cnt, float* acc) {
    int hh = lane >> 5, cl = lane & 31;
    for (int j = 0; j < cnt; j += 32) {
        int s[16];
        float w[16];
#pragma unroll
        for (int u = 0; u < 16; ++u) {
            int e = j + 2 * u + hh;
            s[u] = __shfl(myi, e);
            w[u] = __shfl(myw, e);
        }
        uint32 v[16];
#pragma unroll
        for (int u = 0; u < 16; ++u) v[u] = h16[(size_t)s[u] * 32 + cl];
#pragma unroll
        for (int u = 0; u < 16; ++u) {
            acc[0] = fmaf(w[u], lo16(v[u]), acc[0]);
            acc[1] = fmaf(w[u], hi16(v[u]), acc[1]);
        }
    }
}

// ---------------- GCN gather: one wave per node, bf16 in, bf16 out ----------------
template <int F>
__global__ __launch_bounds__(256) void k_gcn_gather_w(const int2* __restrict__ rseg,
                                                      const int* __restrict__ csr_src,
                                                      const uint32* __restrict__ h16,
                                                      const float* __restrict__ dinv,
                                                      const float* __restrict__ b,
                                                      uint32* __restrict__ out16) {
    int node = blockIdx.x * 4 + (threadIdx.x >> 6);
    int lane = threadIdx.x & 63;
    int2 se = rseg[node];
    int beg = se.x, end = se.y;
    float dd = dinv[node];
    float acc[2] = {0.0f, 0.0f};

    for (int g = beg; g < end; g += 64) {
        int cnt = end - g;
        if (cnt > 64) cnt = 64;
        int myi = node;
        float myw = 0.0f;
        if (lane < cnt) {
            int s = __builtin_nontemporal_load(&csr_src[g + lane]);
            myi = s;
            myw = dinv[s];
        }
        if (F == 128)
            gath128(h16, lane, myi, myw, cnt, acc);
        else
            gath64(h16, lane, myi, myw, cnt, acc);
    }
    if (F == 128) {
        uint32 sv = h16[(size_t)node * 64 + lane];
        acc[0] = fmaf(dd, lo16(sv), acc[0]);
        acc[1] = fmaf(dd, hi16(sv), acc[1]);
        int c = lane * 2;
        float rx = fmaxf(fmaf(acc[0], dd, b[c]), 0.0f);
        float ry = fmaxf(fmaf(acc[1], dd, b[c + 1]), 0.0f);
        out16[(size_t)node * 64 + lane] = pack2(rx, ry);
    } else {
        acc[0] += __shfl_xor(acc[0], 32);
        acc[1] += __shfl_xor(acc[1], 32);
        if (lane < 32) {
            uint32 sv = h16[(size_t)node * 32 + lane];
            acc[0] = fmaf(dd, lo16(sv), acc[0]);
            acc[1] = fmaf(dd, hi16(sv), acc[1]);
            int c = lane * 2;
            float rx = fmaxf(fmaf(acc[0], dd, b[c]), 0.0f);
            float ry = fmaxf(fmaf(acc[1], dd, b[c + 1]), 0.0f);
            out16[(size_t)node * 32 + lane] = pack2(rx, ry);
        }
    }
}

// ---------------- GAT gather: fused softmax, bf16 in, fp32 out (+opt bf16 mirror) -------------
template <int F, bool WB16>
__global__ __launch_bounds__(256) void k_gat_gather_w(const int2* __restrict__ rseg,
                                                      const int* __restrict__ csr_src,
                                                      const uint32* __restrict__ h16,
                                                      const float* __restrict__ asrc,
                                                      const float* __restrict__ adst,
                                                      const float* __restrict__ b,
                                                      float* __restrict__ out,
                                                      uint32* __restrict__ out16) {
    int node = blockIdx.x * 4 + (threadIdx.x >> 6);
    int lane = threadIdx.x & 63;
    int2 se = rseg[node];
    int beg = se.x, end = se.y;
    int deg = end - beg;
    float ad = adst[node];
    float slog = lrelu(asrc[node] + ad);
    float acc[2] = {0.0f, 0.0f};
    float wself;

    if (deg <= 64) {
        int myi = node;
        float logit = -1e30f;
        if (lane < deg) {
            myi = __builtin_nontemporal_load(&csr_src[beg + lane]);
            logit = lrelu(asrc[myi] + ad);
        }
        float m = fmaxf(slog, wave_max(logit));
        float e = (lane < deg) ? __expf(logit - m) : 0.0f;
        float z = wave_sum(e) + __expf(slog - m);
        float zi = 1.0f / z;
        float myw = e * zi;
        wself = __expf(slog - m) * zi;
        if (F == 128)
            gath128(h16, lane, myi, myw, deg, acc);
        else
            gath64(h16, lane, myi, myw, deg, acc);
    } else {
        float lm = slog;
        for (int j = beg + lane; j < end; j += 64) lm = fmaxf(lm, lrelu(asrc[csr_src[j]] + ad));
        float m = wave_max(lm);
        float lz = 0.0f;
        for (int j = beg + lane; j < end; j += 64)
            lz += __expf(lrelu(asrc[csr_src[j]] + ad) - m);
        float z = wave_sum(lz) + __expf(slog - m);
        float zi = 1.0f / z;
        wself = __expf(slog - m) * zi;
        for (int g = beg; g < end; g += 64) {
            int cnt = end - g;
            if (cnt > 64) cnt = 64;
            int myi = node;
            float myw = 0.0f;
            if (lane < cnt) {
                int s = csr_src[g + lane];
                myi = s;
                myw = __expf(lrelu(asrc[s] + ad) - m) * zi;
            }
            if (F == 128)
                gath128(h16, lane, myi, myw, cnt, acc);
            else
                gath64(h16, lane, myi, myw, cnt, acc);
        }
    }
    if (F == 128) {
        uint32 sv = h16[(size_t)node * 64 + lane];
        acc[0] = fmaf(wself, lo16(sv), acc[0]);
        acc[1] = fmaf(wself, hi16(sv), acc[1]);
        int c = lane * 2;
        float2 r;
        r.x = acc[0] + b[c];
        r.y = acc[1] + b[c + 1];
        *(float2*)&out[(size_t)node * 128 + c] = r;
        if (WB16) out16[(size_t)node * 64 + lane] = pack2(r.x, r.y);
    } else {
        acc[0] += __shfl_xor(acc[0], 32);
        acc[1] += __shfl_xor(acc[1], 32);
        if (lane < 32) {
            uint32 sv = h16[(size_t)node * 32 + lane];
            acc[0] = fmaf(wself, lo16(sv), acc[0]);
            acc[1] = fmaf(wself, hi16(sv), acc[1]);
            int c = lane * 2;
            float2 r;
            r.x = acc[0] + b[c];
            r.y = acc[1] + b[c + 1];
            *(float2*)&out[(size_t)node * 64 + c] = r;
            if (WB16) out16[(size_t)node * 32 + lane] = pack2(r.x, r.y);
        }
    }
}

extern "C" void kernel_launch(void* const* d_in, const int* in_sizes, int n_in,
                              void* d_out, int out_size, void* d_ws, size_t ws_size,
                              hipStream_t stream) {
    const float* x = (const float*)d_in[0];
    const int* src = (const int*)d_in[1];
    const int* dst = src + NE;
    const float* W1 = (const float*)d_in[2];
    const float* b1 = (const float*)d_in[3];
    const float* Wg1 = (const float*)d_in[4];
    const float* ag1s = (const float*)d_in[5];
    const float* ag1d = (const float*)d_in[6];
    const float* bg1 = (const float*)d_in[7];
    const float* W2 = (const float*)d_in[8];
    const float* b2 = (const float*)d_in[9];
    const float* Wg2 = (const float*)d_in[10];
    const float* ag2s = (const float*)d_in[11];
    const float* ag2d = (const float*)d_in[12];
    const float* bg2 = (const float*)d_in[13];

    float* enc = (float*)d_out;           // [NN,128]
    float* dec = enc + (size_t)NN * 128;  // [NN,64]

    // workspace layout (all bf16 mirrors padded to NNP rows)
    ushort* m0 = (ushort*)d_ws;                // NNP*128 (xb, later enc16)
    ushort* m1 = m0 + (size_t)NNP * 128;       // NNP*128 (GCN gather out)
    ushort* m2 = m1 + (size_t)NNP * 128;       // NNP*128 (GEMM out mirror)
    ushort* wt1 = m2 + (size_t)NNP * 128;      // 128*128
    ushort* wtg1 = wt1 + 128 * 128;            // 128*128
    ushort* wt2 = wtg1 + 128 * 128;            // 64*128
    ushort* wtg2 = wt2 + 64 * 128;             // 64*64
    float* dinv = (float*)(wtg2 + 64 * 64);    // NN
    float* asrc = dinv + NN;                   // NN
    float* adst = asrc + NN;                   // NN
    int* cnt = (int*)(adst + NN);              // NN
    int* gctr = cnt + NN;                      // 1
    int2* rseg = (int2*)(gctr + 1);            // NN int2
    int* rank = (int*)(rseg + NN);             // NE
    int* csr_src = rank + NE;                  // NE

    const int TB = 256;
    int gE = (NE + TB - 1) / TB;
    int gWave = NN / 4;
    int gM = (NN + 127) / 128;  // 313 mfma-gemm blocks

    // ---- fused casts + zero (x, 4 weights, cnt/gctr) ----
    k_cast<<<dim3((NN * 128 / 4 + TB - 1) / TB, 6), TB, 0, stream>>>(
        x, m0, W1, Wg1, W2, Wg2, wt1, wtg1, wt2, wtg2, cnt, gctr);

    // ---- CSR build: count(+rank) -> alloc -> fill ----
    k_count<<<gE, TB, 0, stream>>>(dst, cnt, rank);
    k_alloc<<<NSB, 256, 0, stream>>>(cnt, gctr, rseg, dinv);
    k_fill<<<gE, TB, 0, stream>>>(src, dst, rank, rseg, csr_src);

    // ---- Layer 1: GCN 128->128 + ReLU ----
    k_gemm_mfma<128, 128, false><<<gM, 256, 0, stream>>>(m0, wt1, m2, nullptr, nullptr, nullptr,
                                                         nullptr);
    k_gcn_gather_w<128><<<gWave, 256, 0, stream>>>(rseg, csr_src, (uint32*)m2, dinv, b1,
                                                   (uint32*)m1);

    // ---- Layer 2: GAT 128->128 -> encoded (fp32) + enc16 mirror (m0) ----
    k_gemm_mfma<128, 128, true><<<gM, 256, 0, stream>>>(m1, wtg1, m2, ag1s, ag1d, asrc, adst);
    k_gat_gather_w<128, true><<<gWave, 256, 0, stream>>>(rseg, csr_src, (uint32*)m2, asrc, adst,
                                                         bg1, enc, (uint32*)m0);

    // ---- Layer 3: GCN 128->64 + ReLU ----
    k_gemm_mfma<128, 64, false><<<gM, 256, 0, stream>>>(m0, wt2, m2, nullptr, nullptr, nullptr,
                                                        nullptr);
    k_gcn_gather_w<64><<<gWave, 256, 0, stream>>>(rseg, csr_src, (uint32*)m2, dinv, b2,
                                                  (uint32*)m1);

    // ---- Layer 4: GAT 64->64 -> decoded (fp32) ----
    k_gemm_mfma<64, 64, true><<<gM, 256, 0, stream>>>(m1, wtg2, m2, ag2s, ag2d, asrc, adst);
    k_gat_gather_w<64, false><<<gWave, 256, 0, stream>>>(rseg, csr_src, (uint32*)m2, asrc, adst,
                                                         bg2, dec, (uint32*)m0);
}

// Round 13
// 211.614 us; speedup vs baseline: 1.0827x; 1.0827x over previous
//
#include <hip/hip_runtime.h>

#define NN 40000
#define NE 640000
#define NSB ((NN + 255) / 256)  // 157 alloc blocks
#define NNP (NN + 64)           // padded rows for OOB-tolerant mfma A loads

typedef unsigned int uint32;
typedef unsigned short ushort;
typedef __attribute__((ext_vector_type(8))) short bf16x8;
typedef __attribute__((ext_vector_type(4))) float f32x4;

static __device__ __forceinline__ float lrelu(float x) { return x > 0.0f ? x : 0.2f * x; }

static __device__ __forceinline__ float wave_max(float v) {
    for (int off = 32; off; off >>= 1) v = fmaxf(v, __shfl_xor(v, off));
    return v;
}
static __device__ __forceinline__ float wave_sum(float v) {
    for (int off = 32; off; off >>= 1) v += __shfl_xor(v, off);
    return v;
}

// bf16 RNE helpers
static __device__ __forceinline__ uint32 bfr(float x) {
    uint32 u = __float_as_uint(x);
    return u + 0x7FFFu + ((u >> 16) & 1u);
}
static __device__ __forceinline__ ushort bf16of(float x) { return (ushort)(bfr(x) >> 16); }
static __device__ __forceinline__ uint32 pack2(float a, float b) {
    return (bfr(a) >> 16) | (bfr(b) & 0xFFFF0000u);
}
static __device__ __forceinline__ float lo16(uint32 v) { return __uint_as_float(v << 16); }
static __device__ __forceinline__ float hi16(uint32 v) { return __uint_as_float(v & 0xFFFF0000u); }

// ------- fused casts + zero init: y=0 x->bf16, y=1..4 weight transpose-casts, y=5 zero -------
__global__ void k_cast(const float* __restrict__ x, ushort* __restrict__ xb,
                       const float* __restrict__ W1, const float* __restrict__ Wg1,
                       const float* __restrict__ W2, const float* __restrict__ Wg2,
                       ushort* __restrict__ t1, ushort* __restrict__ tg1,
                       ushort* __restrict__ t2, ushort* __restrict__ tg2,
                       int* __restrict__ cnt, int* __restrict__ gctr) {
    if (blockIdx.y == 0) {
        int base = (blockIdx.x * 256 + threadIdx.x) * 4;
        if (base < NN * 128) {
            float4 v = *(const float4*)&x[base];
            ushort4 o;
            o.x = bf16of(v.x);
            o.y = bf16of(v.y);
            o.z = bf16of(v.z);
            o.w = bf16of(v.w);
            *(ushort4*)&xb[base] = o;
        }
        return;
    }
    if (blockIdx.y == 5) {
        int i = blockIdx.x * 256 + threadIdx.x;
        if (i < NN) cnt[i] = 0;
        if (i == 0) *gctr = 0;
        return;
    }
    const float* W;
    ushort* T;
    int K, N;
    switch (blockIdx.y) {
        case 1: W = W1; T = t1; K = 128; N = 128; break;
        case 2: W = Wg1; T = tg1; K = 128; N = 128; break;
        case 3: W = W2; T = t2; K = 128; N = 64; break;
        default: W = Wg2; T = tg2; K = 64; N = 64; break;
    }
    int idx = blockIdx.x * 256 + threadIdx.x;
    if (idx < K * N) {
        int n = idx / K, k = idx % K;
        T[idx] = bf16of(W[k * N + n]);
    }
}

// ---------------- CSR build: count(+rank) -> alloc (bump) -> fill (no atomics) ----------------
__global__ void k_count(const int* __restrict__ dst, int* __restrict__ cnt,
                        int* __restrict__ rank) {
    int e = blockIdx.x * blockDim.x + threadIdx.x;
    if (e < NE) rank[e] = atomicAdd(&cnt[dst[e]], 1);
}
__global__ void k_alloc(const int* __restrict__ cnt, int* __restrict__ gctr,
                        int2* __restrict__ rseg, float* __restrict__ dinv) {
    __shared__ int wsums[4];
    __shared__ int sbase;
    int t = threadIdx.x, lane = t & 63, w = t >> 6;
    int i = blockIdx.x * 256 + t;
    int v = (i < NN) ? cnt[i] : 0;
    int x = v;
    for (int off = 1; off < 64; off <<= 1) {
        int u = __shfl_up(x, off);
        if (lane >= off) x += u;
    }
    if (lane == 63) wsums[w] = x;
    __syncthreads();
    if (t == 0) sbase = atomicAdd(gctr, wsums[0] + wsums[1] + wsums[2] + wsums[3]);
    __syncthreads();
    int wofs = 0;
    for (int k = 0; k < w; ++k) wofs += wsums[k];
    int excl = sbase + wofs + x - v;
    if (i < NN) {
        rseg[i] = make_int2(excl, excl + v);
        dinv[i] = rsqrtf(1.0f + (float)v);
    }
}
__global__ void k_fill(const int* __restrict__ src, const int* __restrict__ dst,
                       const int* __restrict__ rank, const int2* __restrict__ rseg,
                       int* __restrict__ csr_src) {
    int e = blockIdx.x * blockDim.x + threadIdx.x;
    if (e < NE) {
        int d = dst[e];
        csr_src[rseg[d].x + rank[e]] = src[e];
    }
}

// ---------------- MFMA GEMM: Y16 = bf16(X*W); GAT: fused asrc/adst epilogue ----------------
template <int FIN, int FOUT, bool GAT>
__global__ __launch_bounds__(256) void k_gemm_mfma(const ushort* __restrict__ Xb,
                                                   const ushort* __restrict__ Wt,
                                                   ushort* __restrict__ Y16,
                                                   const float* __restrict__ a_s,
                                                   const float* __restrict__ a_d,
                                                   float* __restrict__ asrc,
                                                   float* __restrict__ adst) {
    constexpr int NT = FOUT / 16;
    const int w = threadIdx.x >> 6, lane = threadIdx.x & 63;
    const int row0 = blockIdx.x * 128 + w * 32;
    const int lr = lane & 15;
    const int lk = (lane >> 4) * 8;

    f32x4 acc[2][NT];
#pragma unroll
    for (int mt = 0; mt < 2; ++mt)
#pragma unroll
        for (int nt = 0; nt < NT; ++nt) acc[mt][nt] = (f32x4){0.f, 0.f, 0.f, 0.f};

#pragma unroll
    for (int ks = 0; ks < FIN / 32; ++ks) {
        bf16x8 a[2], b[NT];
#pragma unroll
        for (int mt = 0; mt < 2; ++mt)
            a[mt] = *(const bf16x8*)&Xb[(size_t)(row0 + mt * 16 + lr) * FIN + ks * 32 + lk];
#pragma unroll
        for (int nt = 0; nt < NT; ++nt)
            b[nt] = *(const bf16x8*)&Wt[(size_t)(nt * 16 + lr) * FIN + ks * 32 + lk];
#pragma unroll
        for (int mt = 0; mt < 2; ++mt)
#pragma unroll
            for (int nt = 0; nt < NT; ++nt)
                acc[mt][nt] =
                    __builtin_amdgcn_mfma_f32_16x16x32_bf16(a[mt], b[nt], acc[mt][nt], 0, 0, 0);
    }

    const int rbase = (lane >> 4) * 4;
#pragma unroll
    for (int mt = 0; mt < 2; ++mt)
#pragma unroll
        for (int nt = 0; nt < NT; ++nt) {
            int col = nt * 16 + lr;
#pragma unroll
            for (int i = 0; i < 4; ++i) {
                int r = row0 + mt * 16 + rbase + i;
                if (r < NN) Y16[(size_t)r * FOUT + col] = bf16of(acc[mt][nt][i]);
            }
        }

    if (GAT) {
#pragma unroll
        for (int mt = 0; mt < 2; ++mt)
#pragma unroll
            for (int i = 0; i < 4; ++i) {
                float ss = 0.0f, dd = 0.0f;
#pragma unroll
                for (int nt = 0; nt < NT; ++nt) {
                    float v = acc[mt][nt][i];
                    ss = fmaf(v, a_s[nt * 16 + lr], ss);
                    dd = fmaf(v, a_d[nt * 16 + lr], dd);
                }
#pragma unroll
                for (int off = 1; off < 16; off <<= 1) {
                    ss += __shfl_xor(ss, off);
                    dd += __shfl_xor(dd, off);
                }
                if (lr == 0) {
                    int r = row0 + mt * 16 + rbase + i;
                    if (r < NN) {
                        asrc[r] = ss;
                        adst[r] = dd;
                    }
                }
            }
    }
}

// ---- bf16 gather steps: 8 independent loads in flight, fp32 accumulate ----
static __device__ __forceinline__ void gath128(const uint32* __restrict__ h16, int lane, int myi,
                                               float myw, int cnt, float* acc) {
    for (int j = 0; j < cnt; j += 8) {
        int s[8];
        float w[8];
#pragma unroll
        for (int u = 0; u < 8; ++u) {
            s[u] = __shfl(myi, j + u);
            w[u] = __shfl(myw, j + u);
        }
        uint32 v[8];
#pragma unroll
        for (int u = 0; u < 8; ++u) v[u] = h16[(size_t)s[u] * 64 + lane];
#pragma unroll
        for (int u = 0; u < 8; ++u) {
            acc[0] = fmaf(w[u], lo16(v[u]), acc[0]);
            acc[1] = fmaf(w[u], hi16(v[u]), acc[1]);
        }
    }
}
static __device__ __forceinline__ void gath64(const uint32* __restrict__ h16, int lane, int myi,
                                              float myw, int cnt, float* acc) {
    int hh = lane >> 5, cl = lane & 31;
    for (int j = 0; j < cnt; j += 16) {
        int s[8];
        float w[8];
#pragma unroll
        for (int u = 0; u < 8; ++u) {
            int e = j + 2 * u + hh;
            s[u] = __shfl(myi, e);
            w[u] = __shfl(myw, e);
        }
        uint32 v[8];
#pragma unroll
        for (int u = 0; u < 8; ++u) v[u] = h16[(size_t)s[u] * 32 + cl];
#pragma unroll
        for (int u = 0; u < 8; ++u) {
            acc[0] = fmaf(w[u], lo16(v[u]), acc[0]);
            acc[1] = fmaf(w[u], hi16(v[u]), acc[1]);
        }
    }
}

// ---------------- GCN gather: one wave per node, bf16 in, bf16 out ----------------
template <int F>
__global__ __launch_bounds__(256) void k_gcn_gather_w(const int2* __restrict__ rseg,
                                                      const int* __restrict__ csr_src,
                                                      const uint32* __restrict__ h16,
                                                      const float* __restrict__ dinv,
                                                      const float* __restrict__ b,
                                                      uint32* __restrict__ out16) {
    int node = blockIdx.x * 4 + (threadIdx.x >> 6);
    int lane = threadIdx.x & 63;
    int2 se = rseg[node];
    int beg = se.x, end = se.y;
    float dd = dinv[node];
    float acc[2] = {0.0f, 0.0f};

    for (int g = beg; g < end; g += 64) {
        int cnt = end - g;
        if (cnt > 64) cnt = 64;
        int myi = node;
        float myw = 0.0f;
        if (lane < cnt) {
            int s = __builtin_nontemporal_load(&csr_src[g + lane]);
            myi = s;
            myw = dinv[s];
        }
        if (F == 128)
            gath128(h16, lane, myi, myw, cnt, acc);
        else
            gath64(h16, lane, myi, myw, cnt, acc);
    }
    if (F == 128) {
        uint32 sv = h16[(size_t)node * 64 + lane];
        acc[0] = fmaf(dd, lo16(sv), acc[0]);
        acc[1] = fmaf(dd, hi16(sv), acc[1]);
        int c = lane * 2;
        float rx = fmaxf(fmaf(acc[0], dd, b[c]), 0.0f);
        float ry = fmaxf(fmaf(acc[1], dd, b[c + 1]), 0.0f);
        out16[(size_t)node * 64 + lane] = pack2(rx, ry);
    } else {
        acc[0] += __shfl_xor(acc[0], 32);
        acc[1] += __shfl_xor(acc[1], 32);
        if (lane < 32) {
            uint32 sv = h16[(size_t)node * 32 + lane];
            acc[0] = fmaf(dd, lo16(sv), acc[0]);
            acc[1] = fmaf(dd, hi16(sv), acc[1]);
            int c = lane * 2;
            float rx = fmaxf(fmaf(acc[0], dd, b[c]), 0.0f);
            float ry = fmaxf(fmaf(acc[1], dd, b[c + 1]), 0.0f);
            out16[(size_t)node * 32 + lane] = pack2(rx, ry);
        }
    }
}

// ---------------- GAT gather: fused softmax, bf16 in, fp32 out (+opt bf16 mirror) -------------
template <int F, bool WB16>
__global__ __launch_bounds__(256) void k_gat_gather_w(const int2* __restrict__ rseg,
                                                      const int* __restrict__ csr_src,
                                                      const uint32* __restrict__ h16,
                                                      const float* __restrict__ asrc,
                                                      const float* __restrict__ adst,
                                                      const float* __restrict__ b,
                                                      float* __restrict__ out,
                                                      uint32* __restrict__ out16) {
    int node = blockIdx.x * 4 + (threadIdx.x >> 6);
    int lane = threadIdx.x & 63;
    int2 se = rseg[node];
    int beg = se.x, end = se.y;
    int deg = end - beg;
    float ad = adst[node];
    float slog = lrelu(asrc[node] + ad);
    float acc[2] = {0.0f, 0.0f};
    float wself;

    if (deg <= 64) {
        int myi = node;
        float logit = -1e30f;
        if (lane < deg) {
            myi = __builtin_nontemporal_load(&csr_src[beg + lane]);
            logit = lrelu(asrc[myi] + ad);
        }
        float m = fmaxf(slog, wave_max(logit));
        float e = (lane < deg) ? __expf(logit - m) : 0.0f;
        float z = wave_sum(e) + __expf(slog - m);
        float zi = 1.0f / z;
        float myw = e * zi;
        wself = __expf(slog - m) * zi;
        if (F == 128)
            gath128(h16, lane, myi, myw, deg, acc);
        else
            gath64(h16, lane, myi, myw, deg, acc);
    } else {
        float lm = slog;
        for (int j = beg + lane; j < end; j += 64) lm = fmaxf(lm, lrelu(asrc[csr_src[j]] + ad));
        float m = wave_max(lm);
        float lz = 0.0f;
        for (int j = beg + lane; j < end; j += 64)
            lz += __expf(lrelu(asrc[csr_src[j]] + ad) - m);
        float z = wave_sum(lz) + __expf(slog - m);
        float zi = 1.0f / z;
        wself = __expf(slog - m) * zi;
        for (int g = beg; g < end; g += 64) {
            int cnt = end - g;
            if (cnt > 64) cnt = 64;
            int myi = node;
            float myw = 0.0f;
            if (lane < cnt) {
                int s = csr_src[g + lane];
                myi = s;
                myw = __expf(lrelu(asrc[s] + ad) - m) * zi;
            }
            if (F == 128)
                gath128(h16, lane, myi, myw, cnt, acc);
            else
                gath64(h16, lane, myi, myw, cnt, acc);
        }
    }
    if (F == 128) {
        uint32 sv = h16[(size_t)node * 64 + lane];
        acc[0] = fmaf(wself, lo16(sv), acc[0]);
        acc[1] = fmaf(wself, hi16(sv), acc[1]);
        int c = lane * 2;
        float2 r;
        r.x = acc[0] + b[c];
        r.y = acc[1] + b[c + 1];
        *(float2*)&out[(size_t)node * 128 + c] = r;
        if (WB16) out16[(size_t)node * 64 + lane] = pack2(r.x, r.y);
    } else {
        acc[0] += __shfl_xor(acc[0], 32);
        acc[1] += __shfl_xor(acc[1], 32);
        if (lane < 32) {
            uint32 sv = h16[(size_t)node * 32 + lane];
            acc[0] = fmaf(wself, lo16(sv), acc[0]);
            acc[1] = fmaf(wself, hi16(sv), acc[1]);
            int c = lane * 2;
            float2 r;
            r.x = acc[0] + b[c];
            r.y = acc[1] + b[c + 1];
            *(float2*)&out[(size_t)node * 64 + c] = r;
            if (WB16) out16[(size_t)node * 32 + lane] = pack2(r.x, r.y);
        }
    }
}

extern "C" void kernel_launch(void* const* d_in, const int* in_sizes, int n_in,
                              void* d_out, int out_size, void* d_ws, size_t ws_size,
                              hipStream_t stream) {
    const float* x = (const float*)d_in[0];
    const int* src = (const int*)d_in[1];
    const int* dst = src + NE;
    const float* W1 = (const float*)d_in[2];
    const float* b1 = (const float*)d_in[3];
    const float* Wg1 = (const float*)d_in[4];
    const float* ag1s = (const float*)d_in[5];
    const float* ag1d = (const float*)d_in[6];
    const float* bg1 = (const float*)d_in[7];
    const float* W2 = (const float*)d_in[8];
    const float* b2 = (const float*)d_in[9];
    const float* Wg2 = (const float*)d_in[10];
    const float* ag2s = (const float*)d_in[11];
    const float* ag2d = (const float*)d_in[12];
    const float* bg2 = (const float*)d_in[13];

    float* enc = (float*)d_out;           // [NN,128]
    float* dec = enc + (size_t)NN * 128;  // [NN,64]

    // workspace layout (all bf16 mirrors padded to NNP rows)
    ushort* m0 = (ushort*)d_ws;                // NNP*128 (xb, later enc16)
    ushort* m1 = m0 + (size_t)NNP * 128;       // NNP*128 (GCN gather out)
    ushort* m2 = m1 + (size_t)NNP * 128;       // NNP*128 (GEMM out mirror)
    ushort* wt1 = m2 + (size_t)NNP * 128;      // 128*128
    ushort* wtg1 = wt1 + 128 * 128;            // 128*128
    ushort* wt2 = wtg1 + 128 * 128;            // 64*128
    ushort* wtg2 = wt2 + 64 * 128;             // 64*64
    float* dinv = (float*)(wtg2 + 64 * 64);    // NN
    float* asrc = dinv + NN;                   // NN
    float* adst = asrc + NN;                   // NN
    int* cnt = (int*)(adst + NN);              // NN
    int* gctr = cnt + NN;                      // 1
    int2* rseg = (int2*)(gctr + 1);            // NN int2
    int* rank = (int*)(rseg + NN);             // NE
    int* csr_src = rank + NE;                  // NE

    const int TB = 256;
    int gE = (NE + TB - 1) / TB;
    int gWave = NN / 4;
    int gM = (NN + 127) / 128;  // 313 mfma-gemm blocks

    // ---- fused casts + zero (x, 4 weights, cnt/gctr) ----
    k_cast<<<dim3((NN * 128 / 4 + TB - 1) / TB, 6), TB, 0, stream>>>(
        x, m0, W1, Wg1, W2, Wg2, wt1, wtg1, wt2, wtg2, cnt, gctr);

    // ---- CSR build: count(+rank) -> alloc -> fill ----
    k_count<<<gE, TB, 0, stream>>>(dst, cnt, rank);
    k_alloc<<<NSB, 256, 0, stream>>>(cnt, gctr, rseg, dinv);
    k_fill<<<gE, TB, 0, stream>>>(src, dst, rank, rseg, csr_src);

    // ---- Layer 1: GCN 128->128 + ReLU ----
    k_gemm_mfma<128, 128, false><<<gM, 256, 0, stream>>>(m0, wt1, m2, nullptr, nullptr, nullptr,
                                                         nullptr);
    k_gcn_gather_w<128><<<gWave, 256, 0, stream>>>(rseg, csr_src, (uint32*)m2, dinv, b1,
                                                   (uint32*)m1);

    // ---- Layer 2: GAT 128->128 -> encoded (fp32) + enc16 mirror (m0) ----
    k_gemm_mfma<128, 128, true><<<gM, 256, 0, stream>>>(m1, wtg1, m2, ag1s, ag1d, asrc, adst);
    k_gat_gather_w<128, true><<<gWave, 256, 0, stream>>>(rseg, csr_src, (uint32*)m2, asrc, adst,
                                                         bg1, enc, (uint32*)m0);

    // ---- Layer 3: GCN 128->64 + ReLU ----
    k_gemm_mfma<128, 64, false><<<gM, 256, 0, stream>>>(m0, wt2, m2, nullptr, nullptr, nullptr,
                                                        nullptr);
    k_gcn_gather_w<64><<<gWave, 256, 0, stream>>>(rseg, csr_src, (uint32*)m2, dinv, b2,
                                                  (uint32*)m1);

    // ---- Layer 4: GAT 64->64 -> decoded (fp32) ----
    k_gemm_mfma<64, 64, true><<<gM, 256, 0, stream>>>(m1, wtg2, m2, ag2s, ag2d, asrc, adst);
    k_gat_gather_w<64, false><<<gWave, 256, 0, stream>>>(rseg, csr_src, (uint32*)m2, asrc, adst,
                                                         bg2, dec, (uint32*)m0);
}